// Round 14
// baseline (316.102 us; speedup 1.0000x reference)
//
#include <hip/hip_runtime.h>
#include <hip/hip_bf16.h>
#include <math.h>

#define B_    4
#define LQ_   2048
#define LK_   2048
#define D_    1024
#define H_    16
#define LN_EPS_ 1e-5f
#define NEGINF (-__builtin_inff())
#define QSCALE 0.18033688011112042f   // log2(e)/8 — folded into qh at proj

typedef __attribute__((ext_vector_type(8))) short bf16x8;
typedef __attribute__((ext_vector_type(4))) short bf16x4;
typedef __attribute__((ext_vector_type(4))) float f32x4;

#define MFMA(a, b, c) __builtin_amdgcn_mfma_f32_16x16x32_bf16(a, b, c, 0, 0, 0)

#if __has_builtin(__builtin_amdgcn_exp2f)
#define EXP2(x) __builtin_amdgcn_exp2f(x)
#else
#define EXP2(x) __expf((x) * 0.6931471805599453f)
#endif

__device__ __forceinline__ short f2bf(float f) {
    union { __hip_bfloat16 h; short s; } u;
    u.h = __float2bfloat16(f);
    return u.s;
}

__device__ __forceinline__ float bf2f(short s) {
    union { float f; unsigned u; } z;
    z.u = ((unsigned)(unsigned short)s) << 16;
    return z.f;
}

__device__ __forceinline__ void gld16(const short* g, short* l) {
    __builtin_amdgcn_global_load_lds(
        (const __attribute__((address_space(1))) void*)g,
        (__attribute__((address_space(3))) void*)l, 16, 0, 0);
}

// XCD-aware bijective block remap (T1).  n8 = (gx*gy)/8 per z-slice.
__device__ __forceinline__ void xcd_swz(int gx, int n8, int* bx, int* by) {
    const int lin = *bx + gx * (*by);        // XCD = lin&7
    const int nl  = (lin & 7) * n8 + (lin >> 3);
    *bx = nl % gx;
    *by = nl / gx;
}

// ---------------------------------------------------------------------------
// scan: per batch, compact unmasked key indices + both additive masks.
// ---------------------------------------------------------------------------
__global__ __launch_bounds__(256) void scan_kernel(
    const int* __restrict__ mask, int* __restrict__ idx, int* __restrict__ pos,
    int* __restrict__ cnt, float* __restrict__ maskc, float* __restrict__ maskf)
{
    const int b = blockIdx.x;
    const int t = threadIdx.x;
    const int lane = t & 63, wid = t >> 6;
    __shared__ int wsum[4];
    const int base = b * 2048 + t * 8;

    int fl[8]; int loc = 0;
    #pragma unroll
    for (int j = 0; j < 8; ++j) { fl[j] = (mask[base + j] == 0) ? 1 : 0; loc += fl[j]; }

    int inc = loc;
    #pragma unroll
    for (int d = 1; d < 64; d <<= 1) {
        const int n = __shfl_up(inc, d);
        if (lane >= d) inc += n;
    }
    if (lane == 63) wsum[wid] = inc;
    __syncthreads();
    int wbase = 0;
    for (int i = 0; i < wid; ++i) wbase += wsum[i];
    const int total = wsum[0] + wsum[1] + wsum[2] + wsum[3];

    int e = wbase + inc - loc;   // exclusive prefix for this thread
    #pragma unroll
    for (int j = 0; j < 8; ++j) {
        const int p = t * 8 + j;
        if (fl[j]) { idx[b * 2048 + e] = p; pos[base + j] = e; ++e; }
        else        pos[base + j] = -1;
        maskc[base + j] = (p < total) ? 0.f : NEGINF;
        maskf[base + j] = fl[j] ? 0.f : NEGINF;
        if (p >= total) idx[base + j] = 0;   // pad-safe gather source
    }
    if (t == 0) cnt[b] = total;
}

// ---------------------------------------------------------------------------
// cast_wt: W[k][n] f32 -> Wt[n][k] bf16 (transposed), 64x64 LDS tiles.
// ---------------------------------------------------------------------------
__global__ __launch_bounds__(256) void cast_wt_kernel(
    const float* __restrict__ Wq, const float* __restrict__ Wk,
    const float* __restrict__ Wv, const float* __restrict__ Wo,
    short* __restrict__ Wtq, short* __restrict__ Wtk,
    short* __restrict__ Wtv, short* __restrict__ Wto)
{
    const int which = blockIdx.z;
    const float* W = which == 0 ? Wq : (which == 1 ? Wk : (which == 2 ? Wv : Wo));
    short* Wt      = which == 0 ? Wtq : (which == 1 ? Wtk : (which == 2 ? Wtv : Wto));

    __shared__ float T[64][65];
    const int t = threadIdx.x;
    const int k0 = blockIdx.x * 64, n0 = blockIdx.y * 64;
    {
        const int row = t >> 2, cq = (t & 3) * 16;
        #pragma unroll
        for (int i = 0; i < 4; ++i) {
            const float4 v4 = *reinterpret_cast<const float4*>(&W[(size_t)(k0 + row) * 1024 + n0 + cq + i * 4]);
            T[row][cq + i * 4 + 0] = v4.x; T[row][cq + i * 4 + 1] = v4.y;
            T[row][cq + i * 4 + 2] = v4.z; T[row][cq + i * 4 + 3] = v4.w;
        }
    }
    __syncthreads();
    const int nl = t >> 2, kq = (t & 3) * 16;
    bf16x8 o0, o1;
    #pragma unroll
    for (int j = 0; j < 8; ++j) {
        o0[j] = f2bf(T[kq + j][nl]);
        o1[j] = f2bf(T[kq + 8 + j][nl]);
    }
    *reinterpret_cast<bf16x8*>(&Wt[(size_t)(n0 + nl) * 1024 + k0 + kq]) = o0;
    *reinterpret_cast<bf16x8*>(&Wt[(size_t)(n0 + nl) * 1024 + k0 + kq + 8]) = o1;
}

// ---------------------------------------------------------------------------
// proj: C = X(f32, read DIRECT)[M=8192,K=1024] @ Wt^T + bias.  128x128 tile,
// BK=32.  A staged as f32 via gld16 with chunk-XOR swizzle (row&7 over 8x16B
// chunks; 128B rows = exact bank wrap otherwise); converted to bf16 at frag
// load (proj VALUBusy was 15% — slack).  Numerics identical to cast_x path.
// XCD-swizzled.  which: 0->qh (scaled), 1->kh, 2->vT_c (compacted via pos).
// ---------------------------------------------------------------------------
__global__ __launch_bounds__(256) void proj_kernel(
    const float* __restrict__ Xq, const float* __restrict__ Xk, const float* __restrict__ Xv,
    const short* __restrict__ Wtq, const short* __restrict__ Wtk, const short* __restrict__ Wtv,
    const float* __restrict__ bq, const float* __restrict__ bk, const float* __restrict__ bv,
    const int* __restrict__ pos,
    short* __restrict__ qh, short* __restrict__ kh, short* __restrict__ vTc)
{
    const int which = blockIdx.z;
    const float* A  = which == 0 ? Xq : (which == 1 ? Xk : Xv);
    const short* Bt = which == 0 ? Wtq : (which == 1 ? Wtk : Wtv);
    const float* bias = which == 0 ? bq : (which == 1 ? bk : bv);

    __shared__ float AlF[4096];  // [128 rows m][32 k] f32, chunk-swizzled (16KB)
    __shared__ short Bl[4096];   // [128 rows n][32 k] bf16, swizzled chunks (8KB)

    const int t = threadIdx.x;
    const int lane = t & 63, w = t >> 6;
    const int wm = w >> 1, wn = w & 1;
    const int g = lane >> 4, r16 = lane & 15;

    int bx = blockIdx.x, by = blockIdx.y;     // (8 n, 64 m)
    xcd_swz(8, 64, &bx, &by);
    const int m0 = by * 128, n0 = bx * 128;

    f32x4 acc[4][4] = {};

    for (int k0 = 0; k0 < 1024; k0 += 32) {
        __syncthreads();
        // A: 128 rows x 8 chunks of 4 f32; LDS chunk (row,col) holds global
        // chunk col^(row&7).  4 gld16/thread.
        #pragma unroll
        for (int j = 0; j < 4; ++j) {
            const int c = j * 256 + t;
            const int row = c >> 3, col = c & 7;
            const int scol = col ^ (row & 7);
            gld16((const short*)(A + (size_t)(m0 + row) * 1024 + k0 + scol * 4),
                  (short*)AlF + (size_t)c * 8);
        }
        // B: unchanged bf16 staging
        #pragma unroll
        for (int i = 0; i < 2; ++i) {
            const int row = i * 64 + (t >> 2);
            const int cl = (t & 3) ^ ((row >> 1) & 3);
            gld16(Bt + (size_t)(n0 + row) * 1024 + k0 + cl * 8, Bl + i * 2048 + t * 8);
        }
        __syncthreads();

        bf16x8 af[4], bf[4];
        #pragma unroll
        for (int mf = 0; mf < 4; ++mf) {
            const int row = wm * 64 + mf * 16 + r16;
            const int c0 = (2 * g) ^ (row & 7);
            const int c1 = (2 * g + 1) ^ (row & 7);
            const f32x4 a0 = *reinterpret_cast<const f32x4*>(AlF + row * 32 + c0 * 4);
            const f32x4 a1 = *reinterpret_cast<const f32x4*>(AlF + row * 32 + c1 * 4);
            bf16x8 a8;
            #pragma unroll
            for (int r = 0; r < 4; ++r) { a8[r] = f2bf(a0[r]); a8[4 + r] = f2bf(a1[r]); }
            af[mf] = a8;
        }
        #pragma unroll
        for (int nf = 0; nf < 4; ++nf) {
            const int row = wn * 64 + nf * 16 + r16;
            bf[nf] = *reinterpret_cast<const bf16x8*>(
                (const char*)Bl + row * 64 + (((g ^ ((row >> 1) & 3))) << 4));
        }
        #pragma unroll
        for (int mf = 0; mf < 4; ++mf)
            #pragma unroll
            for (int nf = 0; nf < 4; ++nf)
                acc[mf][nf] = MFMA(af[mf], bf[nf], acc[mf][nf]);
    }

    if (which < 2) {
        #pragma unroll
        for (int nf = 0; nf < 4; ++nf) {
            const int n = n0 + wn * 64 + nf * 16 + r16;
            const int h = n >> 6, dh = n & 63;
            const float bn = bias[n];
            #pragma unroll
            for (int mf = 0; mf < 4; ++mf) {
                #pragma unroll
                for (int r = 0; r < 4; ++r) {
                    const int m = m0 + wm * 64 + mf * 16 + 4 * g + r;
                    const int bb = m >> 11, l = m & 2047;
                    float vf = acc[mf][nf][r] + bn;
                    if (which == 0) vf *= QSCALE;       // base-2 logit domain
                    ((which == 0) ? qh : kh)[(((size_t)(bb * H_ + h)) * LQ_ + l) * 64 + dh] = f2bf(vf);
                }
            }
        }
    } else {
        int posr[4][4], bbr[4][4];
        #pragma unroll
        for (int mf = 0; mf < 4; ++mf)
            #pragma unroll
            for (int r = 0; r < 4; ++r) {
                const int m = m0 + wm * 64 + mf * 16 + 4 * g + r;
                const int bb = m >> 11, l = m & 2047;
                bbr[mf][r] = bb;
                posr[mf][r] = pos[bb * 2048 + l];
            }
        #pragma unroll
        for (int nf = 0; nf < 4; ++nf) {
            const int n = n0 + wn * 64 + nf * 16 + r16;
            const int h = n >> 6, dh = n & 63;
            const float bn = bias[n];
            #pragma unroll
            for (int mf = 0; mf < 4; ++mf) {
                #pragma unroll
                for (int r = 0; r < 4; ++r) {
                    const int pc = posr[mf][r];
                    if (pc >= 0)
                        vTc[(((size_t)(bbr[mf][r] * H_ + h)) * 64 + dh) * (size_t)LK_ + pc] =
                            f2bf(acc[mf][nf][r] + bn);
                }
            }
        }
    }
}

// ---------------------------------------------------------------------------
// flash: swapped-QK^T MFMA attention over COMPACTED keys.  8 waves / 128 q
// per block sharing the staged K/V tiles.  XCD-swizzled.  (round-13 proven)
// ---------------------------------------------------------------------------
__global__ __launch_bounds__(512) void flash_kernel(
    const short* __restrict__ qh, const short* __restrict__ kh, const short* __restrict__ vTc,
    const int* __restrict__ idx, const int* __restrict__ cnt, const float* __restrict__ maskc,
    short* __restrict__ ctx, float* __restrict__ mOut, float* __restrict__ sOut)
{
    int bx = blockIdx.x, by = blockIdx.y;     // (16 q, 16 h) = 256/slice
    xcd_swz(16, 32, &bx, &by);
    const int q0 = bx * 128;
    const int h  = by;
    const int b  = blockIdx.z;

    __shared__ short Kl[2][4096];   // [64 k_c][64 d] bf16, 16B-chunk swizzle (^row&7)
    __shared__ short Vl[2][4096];   // [64 dv][64 k_c] bf16, same swizzle

    const int t = threadIdx.x;
    const int lane = t & 63, w = t >> 6;     // 8 waves, wave owns q-rows w*16..w*16+15
    const int g = lane >> 4, q16 = lane & 15;

    const short* kbase = kh + (size_t)(b * H_ + h) * LK_ * 64;
    const short* vbase = vTc + (size_t)(b * H_ + h) * 64 * (size_t)LK_;
    const int*   idxb  = idx + b * 2048;
    const int nt = (cnt[b] + 63) >> 6;

    bf16x8 qf0, qf1;
    {
        const short* qrow = qh + ((size_t)(b * H_ + h) * LQ_ + q0 + w * 16 + q16) * 64;
        qf0 = *reinterpret_cast<const bf16x8*>(qrow + 8 * g);
        qf1 = *reinterpret_cast<const bf16x8*>(qrow + 32 + 8 * g);
    }

    f32x4 mlast[4] = {};
    if (nt > 0) {
        #pragma unroll
        for (int kb = 0; kb < 4; ++kb)
            mlast[kb] = *reinterpret_cast<const f32x4*>(
                maskc + b * 2048 + (nt - 1) * 64 + kb * 16 + 4 * g);
    }

    // staging map: 512 threads x 16B each = one full 64x64 bf16 tile
    const int srw = t >> 3, scl = t & 7;
    const int cl = scl ^ (srw & 7);

    f32x4 ot[4] = {};             // O^T frags: dv = 16*fc + 4g + r, q = q16
    float m_run = NEGINF, l_run = 0.f;

    if (nt > 0) {                 // prologue: stage compacted tile 0
        const int orig = idxb[srw];
        gld16(kbase + (size_t)orig * 64 + cl * 8, Kl[0] + t * 8);
        gld16(vbase + (size_t)srw * LK_ + cl * 8, Vl[0] + t * 8);
    }
    __syncthreads();

    int cur = 0;
    for (int kt = 0; kt < nt; ++kt) {
        if (kt + 1 < nt) {        // issue next tile's staging
            const int kn = (kt + 1) * 64;
            const int orig = idxb[kn + srw];
            gld16(kbase + (size_t)orig * 64 + cl * 8, Kl[cur ^ 1] + t * 8);
            gld16(vbase + (size_t)srw * LK_ + kn + cl * 8, Vl[cur ^ 1] + t * 8);
        }
        const bool lastt = (kt == nt - 1);

        // --- QK^T (swapped): S^T[k][q]; C-init = pad mask on last tile ---
        float lg[4][4];
        const short* klp = Kl[cur];
        __builtin_amdgcn_s_setprio(1);
        #pragma unroll
        for (int kb = 0; kb < 4; ++kb) {
            const int krow = kb * 16 + q16;
            const char* rowp = (const char*)klp + krow * 128;
            const int sw = (krow & 7) << 4;
            const bf16x8 kf0 = *reinterpret_cast<const bf16x8*>(rowp + ((g << 4) ^ sw));
            const bf16x8 kf1 = *reinterpret_cast<const bf16x8*>(rowp + (((4 + g) << 4) ^ sw));
            f32x4 s = lastt ? mlast[kb] : (f32x4){0.f, 0.f, 0.f, 0.f};
            s = MFMA(kf0, qf0, s);
            s = MFMA(kf1, qf1, s);
            #pragma unroll
            for (int r = 0; r < 4; ++r) lg[kb][r] = s[r];
        }
        __builtin_amdgcn_s_setprio(0);

        // --- online softmax (base-2), defer-rescale THR=8 ---
        float tm = NEGINF;
        #pragma unroll
        for (int kb = 0; kb < 4; ++kb)
            #pragma unroll
            for (int r = 0; r < 4; ++r) tm = fmaxf(tm, lg[kb][r]);
        tm = fmaxf(tm, __shfl_xor(tm, 16));
        tm = fmaxf(tm, __shfl_xor(tm, 32));

        const bool skip = __all(tm <= m_run + 8.0f);
        if (!skip) {
            const float m_new = fmaxf(m_run, tm);
            const float alpha = (m_run == NEGINF) ? 0.f : EXP2(m_run - m_new);
            #pragma unroll
            for (int fc = 0; fc < 4; ++fc)
                #pragma unroll
                for (int r = 0; r < 4; ++r) ot[fc][r] *= alpha;
            l_run *= alpha;
            m_run = m_new;
        }
        const float m_use = (m_run == NEGINF) ? 0.f : m_run;

        float p[4][4];
        float ls = 0.f;
        #pragma unroll
        for (int kb = 0; kb < 4; ++kb)
            #pragma unroll
            for (int r = 0; r < 4; ++r) { p[kb][r] = EXP2(lg[kb][r] - m_use); ls += p[kb][r]; }
        ls += __shfl_xor(ls, 16);
        ls += __shfl_xor(ls, 32);
        l_run += ls;

        // pack P^T to bf16 B-frags (k-bijection matches V^T A-frags)
        bf16x8 pb[2];
        #pragma unroll
        for (int r = 0; r < 4; ++r) {
            pb[0][r]     = f2bf(p[0][r]);
            pb[0][4 + r] = f2bf(p[1][r]);
            pb[1][r]     = f2bf(p[2][r]);
            pb[1][4 + r] = f2bf(p[3][r]);
        }

        // --- PV: O^T[dv][q] += mfma(V^T, P^T) ---
        const short* vlp = Vl[cur];
        __builtin_amdgcn_s_setprio(1);
        #pragma unroll
        for (int fc = 0; fc < 4; ++fc) {
            const int dvrow = fc * 16 + q16;
            const char* rowp = (const char*)vlp + dvrow * 128;
            const int sw = (dvrow & 7) << 4;
            #pragma unroll
            for (int tt = 0; tt < 2; ++tt) {
                const bf16x4 va = *reinterpret_cast<const bf16x4*>(rowp + ((64 * tt + 8 * g) ^ sw));
                const bf16x4 vb = *reinterpret_cast<const bf16x4*>(rowp + ((64 * tt + 32 + 8 * g) ^ sw));
                bf16x8 af;
                af[0] = va[0]; af[1] = va[1]; af[2] = va[2]; af[3] = va[3];
                af[4] = vb[0]; af[5] = vb[1]; af[6] = vb[2]; af[7] = vb[3];
                ot[fc] = MFMA(af, pb[tt], ot[fc]);
            }
        }
        __builtin_amdgcn_s_setprio(0);

        __syncthreads();   // drains next-tile gld16s; next iter reads cur^1
        cur ^= 1;
    }

    const float rs = (l_run > 0.f) ? 1.0f / l_run : 0.f;
    short* crow = ctx + ((size_t)b * LQ_ + q0 + w * 16 + q16) * (size_t)(H_ * 64) + h * 64;
    #pragma unroll
    for (int fc = 0; fc < 4; ++fc) {
        bf16x4 o4;
        #pragma unroll
        for (int r = 0; r < 4; ++r) o4[r] = f2bf(ot[fc][r] * rs);
        *reinterpret_cast<bf16x4*>(crow + fc * 16 + 4 * g) = o4;
    }
    if (lane < 16) {
        const size_t idxo = (size_t)(b * H_ + h) * LQ_ + q0 + w * 16 + lane;
        mOut[idxo] = m_run;
        sOut[idxo] = l_run;
    }
}

// ---------------------------------------------------------------------------
// avg: FULL-K, per-head K dbuf, 512 threads / 8 waves / 128 q-rows per block
// sharing the staged K-tile.  (round-8 proven kernel, verbatim — 92 us)
// ---------------------------------------------------------------------------
__global__ __launch_bounds__(512) void avg_kernel(
    const short* __restrict__ qh, const short* __restrict__ kh,
    const float* __restrict__ maskf,
    const float* __restrict__ mS, const float* __restrict__ sS,
    float* __restrict__ attn_avg)
{
    const int k0 = blockIdx.x * 64;
    const int q0 = blockIdx.y * 128;
    const int b  = blockIdx.z;

    __shared__ short Kl[2][4096];   // [buf][64 k x 64 d], 8KB each

    const int t = threadIdx.x;
    const int lane = t & 63, w = t >> 6;          // 8 waves
    const int g = lane >> 4, q16 = lane & 15;

    f32x4 mk[4];
    #pragma unroll
    for (int kb = 0; kb < 4; ++kb)
        mk[kb] = *reinterpret_cast<const f32x4*>(maskf + b * LK_ + k0 + kb * 16 + 4 * g);

    // staging map: 512 threads x 16B = full 64x64 bf16 tile, one gld16 each
    const int srw = t >> 3, scl = t & 7;          // row 0..63, chunk 0..7
    const int cl = scl ^ (srw & 7);
    const short* kbb = kh + ((size_t)b * H_ * LK_ + k0) * 64;   // + h*LK_*64

    const short* qbase = qh + ((size_t)b * H_ * LQ_ + q0 + w * 16 + q16) * 64;  // h-stride LQ_*64
    const size_t stbase = (size_t)b * H_ * LQ_ + q0 + w * 16 + q16;             // h-stride LQ_

    {   // prologue: stage head 0
        gld16(kbb + (size_t)srw * 64 + cl * 8, Kl[0] + t * 8);
    }
    bf16x8 qc0 = *reinterpret_cast<const bf16x8*>(qbase + 8 * g);
    bf16x8 qc1 = *reinterpret_cast<const bf16x8*>(qbase + 32 + 8 * g);
    float mc = mS[stbase], sc = sS[stbase];
    __syncthreads();

    f32x4 acc[4] = {};
    int cur = 0;
    for (int hh = 0; hh < H_; ++hh) {
        bf16x8 qn0, qn1; float mn = 0.f, sn = 0.f;
        if (hh + 1 < H_) {
            gld16(kbb + (size_t)(hh + 1) * LK_ * 64 + (size_t)srw * 64 + cl * 8,
                  Kl[cur ^ 1] + t * 8);
            const short* qp = qbase + (size_t)(hh + 1) * LQ_ * 64;
            qn0 = *reinterpret_cast<const bf16x8*>(qp + 8 * g);
            qn1 = *reinterpret_cast<const bf16x8*>(qp + 32 + 8 * g);
            mn = mS[stbase + (size_t)(hh + 1) * LQ_];
            sn = sS[stbase + (size_t)(hh + 1) * LQ_];
        }

        // fold 1/s into the exponent: exp2(l - m - log2 s)
        const float madj = (mc == NEGINF || sc <= 0.f)
                               ? __builtin_inff() : mc + __log2f(sc);

        const short* klp = Kl[cur];
        __builtin_amdgcn_s_setprio(1);
        #pragma unroll
        for (int kb = 0; kb < 4; ++kb) {
            const int krow = kb * 16 + q16;
            const char* rowp = (const char*)klp + krow * 128;
            const int sw = (krow & 7) << 4;
            const bf16x8 kf0 = *reinterpret_cast<const bf16x8*>(rowp + ((g << 4) ^ sw));
            const bf16x8 kf1 = *reinterpret_cast<const bf16x8*>(rowp + (((4 + g) << 4) ^ sw));
            f32x4 s = mk[kb];
            s = MFMA(kf0, qc0, s);
            s = MFMA(kf1, qc1, s);
            #pragma unroll
            for (int r = 0; r < 4; ++r)
                acc[kb][r] += EXP2(s[r] - madj);
        }
        __builtin_amdgcn_s_setprio(0);

        __syncthreads();   // drains next-head gld16; safe to flip buffers
        if (hh + 1 < H_) { qc0 = qn0; qc1 = qn1; mc = mn; sc = sn; }
        cur ^= 1;
    }

    const float scale = 1.0f / (float)H_;
    float* orow = attn_avg + ((size_t)b * LQ_ + q0 + w * 16 + q16) * (size_t)LK_ + k0;
    #pragma unroll
    for (int kb = 0; kb < 4; ++kb) {
        f32x4 o = acc[kb];
        o[0] *= scale; o[1] *= scale; o[2] *= scale; o[3] *= scale;
        *reinterpret_cast<f32x4*>(orow + kb * 16 + 4 * g) = o;
    }
}

// ---------------------------------------------------------------------------
// outproj: preln(bf16) = ctx(bf16) @ WoT^T + bo + resid.  XCD-swizzled.
// ---------------------------------------------------------------------------
__global__ __launch_bounds__(256) void outproj_kernel(
    const short* __restrict__ ctxIn, const short* __restrict__ Wto,
    const float* __restrict__ bo, const float* __restrict__ resid,
    short* __restrict__ preln)
{
    __shared__ short Al[4096];
    __shared__ short Bl[4096];

    const int t = threadIdx.x;
    const int lane = t & 63, w = t >> 6;
    const int wm = w >> 1, wn = w & 1;
    const int g = lane >> 4, r16 = lane & 15;

    int bx = blockIdx.x, by = blockIdx.y;     // (8 n, 64 m)
    xcd_swz(8, 64, &bx, &by);
    const int m0 = by * 128, n0 = bx * 128;

    f32x4 acc[4][4] = {};

    for (int k0 = 0; k0 < 1024; k0 += 32) {
        __syncthreads();
        #pragma unroll
        for (int i = 0; i < 2; ++i) {
            const int row = i * 64 + (t >> 2);
            const int cl = (t & 3) ^ ((row >> 1) & 3);
            gld16(ctxIn + (size_t)(m0 + row) * 1024 + k0 + cl * 8, Al + i * 2048 + t * 8);
            gld16(Wto   + (size_t)(n0 + row) * 1024 + k0 + cl * 8, Bl + i * 2048 + t * 8);
        }
        __syncthreads();

        bf16x8 af[4], bf[4];
        #pragma unroll
        for (int mf = 0; mf < 4; ++mf) {
            const int row = wm * 64 + mf * 16 + r16;
            af[mf] = *reinterpret_cast<const bf16x8*>(
                (const char*)Al + row * 64 + (((g ^ ((row >> 1) & 3))) << 4));
        }
        #pragma unroll
        for (int nf = 0; nf < 4; ++nf) {
            const int row = wn * 64 + nf * 16 + r16;
            bf[nf] = *reinterpret_cast<const bf16x8*>(
                (const char*)Bl + row * 64 + (((g ^ ((row >> 1) & 3))) << 4));
        }
        #pragma unroll
        for (int mf = 0; mf < 4; ++mf)
            #pragma unroll
            for (int nf = 0; nf < 4; ++nf)
                acc[mf][nf] = MFMA(af[mf], bf[nf], acc[mf][nf]);
    }

    #pragma unroll
    for (int nf = 0; nf < 4; ++nf) {
        const int n = n0 + wn * 64 + nf * 16 + r16;
        const float bn = bo[n];
        #pragma unroll
        for (int mf = 0; mf < 4; ++mf) {
            #pragma unroll
            for (int r = 0; r < 4; ++r) {
                const size_t m = m0 + wm * 64 + mf * 16 + 4 * g + r;
                preln[m * 1024 + n] = f2bf(acc[mf][nf][r] + bn + resid[m * 1024 + n]);
            }
        }
    }
}

// ---------------------------------------------------------------------------
// ln: LayerNorm over D=1024 from bf16 preln, one block per row, f32 out.
// ---------------------------------------------------------------------------
__global__ __launch_bounds__(256) void ln_kernel(
    const short* __restrict__ xin, const float* __restrict__ gam,
    const float* __restrict__ bet, float* __restrict__ out)
{
    const size_t row = blockIdx.x;
    const int t = threadIdx.x;
    const bf16x4 pv = *reinterpret_cast<const bf16x4*>(&xin[row * 1024 + t * 4]);
    float x[4];
    #pragma unroll
    for (int j = 0; j < 4; ++j) x[j] = bf2f(pv[j]);

    float s  = x[0] + x[1] + x[2] + x[3];
    float ss = x[0] * x[0] + x[1] * x[1] + x[2] * x[2] + x[3] * x[3];
    #pragma unroll
    for (int w = 1; w < 64; w <<= 1) { s += __shfl_xor(s, w); ss += __shfl_xor(ss, w); }

    __shared__ float rs_[4], rss_[4];
    if ((t & 63) == 0) { rs_[t >> 6] = s; rss_[t >> 6] = ss; }
    __syncthreads();
    s  = rs_[0] + rs_[1] + rs_[2] + rs_[3];
    ss = rss_[0] + rss_[1] + rss_[2] + rss_[3];

    const float mean = s * (1.0f / 1024.0f);
    const float var  = ss * (1.0f / 1024.0f) - mean * mean;
    const float rstd = rsqrtf(var + LN_EPS_);

    const float4 g4 = *reinterpret_cast<const float4*>(&gam[t * 4]);
    const float4 b4 = *reinterpret_cast<const float4*>(&bet[t * 4]);
    float4 o;
    o.x = (x[0] - mean) * rstd * g4.x + b4.x;
    o.y = (x[1] - mean) * rstd * g4.y + b4.y;
    o.z = (x[2] - mean) * rstd * g4.z + b4.z;
    o.w = (x[3] - mean) * rstd * g4.w + b4.w;
    *reinterpret_cast<float4*>(&out[row * 1024 + t * 4]) = o;
}

// ---------------------------------------------------------------------------
extern "C" void kernel_launch(void* const* d_in, const int* in_sizes, int n_in,
                              void* d_out, int out_size, void* d_ws, size_t ws_size,
                              hipStream_t stream)
{
    const float* q    = (const float*)d_in[0];
    const float* k    = (const float*)d_in[1];
    const float* v    = (const float*)d_in[2];
    const int*   mask = (const int*)d_in[3];
    const float* Wq   = (const float*)d_in[4];
    const float* bq   = (const float*)d_in[5];
    const float* Wk   = (const float*)d_in[6];
    const float* bk   = (const float*)d_in[7];
    const float* Wv   = (const float*)d_in[8];
    const float* bv   = (const float*)d_in[9];
    const float* Wo   = (const float*)d_in[10];
    const float* bo   = (const float*)d_in[11];
    const float* lng  = (const float*)d_in[12];
    const float* lnb  = (const float*)d_in[13];

    float* out      = (float*)d_out;                    // [B,LQ,D]
    float* attn_avg = out + (size_t)B_ * LQ_ * D_;      // [B,LQ,LK]

    const size_t XSZ = (size_t)B_ * LQ_ * D_;           // 8388608 elements
    const size_t WSZ = (size_t)D_ * D_;                 // 1048576

    short* Xpad = (short*)d_ws;                         // former Xq/Xk/Xv (unused)
    short* Wtq = Xpad + 3 * XSZ;
    short* Wtk = Wtq + WSZ;
    short* Wtv = Wtk + WSZ;
    short* Wto = Wtv + WSZ;
    short* qh  = Wto + WSZ;                             // [B,H,LQ,64] bf16 (pre-scaled)
    short* kh  = qh + XSZ;
    short* vTc = kh + XSZ;                              // [B,H,64,LK] bf16, COMPACTED cols
    float* mSt = (float*)(vTc + XSZ);                   // [B,H,LQ] base-2 max
    float* sSt = mSt + (size_t)B_ * H_ * LQ_;
    float* maskf = sSt + (size_t)B_ * H_ * LQ_;         // [B,LK] additive (full)
    float* maskc = maskf + (size_t)B_ * LK_;            // [B,LK] additive (compacted+pad)
    int*   idx   = (int*)(maskc + (size_t)B_ * LK_);    // [B,LK] compacted -> orig
    int*   pos   = idx + (size_t)B_ * LK_;              // [B,LK] orig -> compacted / -1
    int*   cnt   = pos + (size_t)B_ * LK_;              // [B]
    short* preln = qh;          // bf16, overlays qh (dead after avg)
    short* ctx   = Xpad;        // overlays unused X region

    scan_kernel<<<dim3(B_), 256, 0, stream>>>(mask, idx, pos, cnt, maskc, maskf);
    cast_wt_kernel<<<dim3(16, 16, 4), 256, 0, stream>>>(Wq, Wk, Wv, Wo, Wtq, Wtk, Wtv, Wto);

    proj_kernel<<<dim3(8, 64, 3), 256, 0, stream>>>(q, k, v, Wtq, Wtk, Wtv,
                                                    bq, bk, bv, pos, qh, kh, vTc);

    flash_kernel<<<dim3(16, 16, 4), 512, 0, stream>>>(qh, kh, vTc, idx, cnt, maskc,
                                                      ctx, mSt, sSt);

    avg_kernel<<<dim3(32, 16, 4), 512, 0, stream>>>(qh, kh, maskf, mSt, sSt, attn_avg);

    outproj_kernel<<<dim3(8, 64), 256, 0, stream>>>(ctx, Wto, bo, q, preln);

    ln_kernel<<<8192, 256, 0, stream>>>(preln, lng, lnb, out);
}

// Round 15
// 304.208 us; speedup vs baseline: 1.0391x; 1.0391x over previous
//
#include <hip/hip_runtime.h>
#include <hip/hip_bf16.h>
#include <math.h>

#define B_    4
#define LQ_   2048
#define LK_   2048
#define D_    1024
#define H_    16
#define LN_EPS_ 1e-5f
#define NEGINF (-__builtin_inff())
#define QSCALE 0.18033688011112042f   // log2(e)/8 — folded into qh at proj

typedef __attribute__((ext_vector_type(8))) short bf16x8;
typedef __attribute__((ext_vector_type(4))) short bf16x4;
typedef __attribute__((ext_vector_type(4))) float f32x4;

#define MFMA(a, b, c) __builtin_amdgcn_mfma_f32_16x16x32_bf16(a, b, c, 0, 0, 0)

#if __has_builtin(__builtin_amdgcn_exp2f)
#define EXP2(x) __builtin_amdgcn_exp2f(x)
#else
#define EXP2(x) __expf((x) * 0.6931471805599453f)
#endif

__device__ __forceinline__ short f2bf(float f) {
    union { __hip_bfloat16 h; short s; } u;
    u.h = __float2bfloat16(f);
    return u.s;
}

__device__ __forceinline__ float bf2f(short s) {
    union { float f; unsigned u; } z;
    z.u = ((unsigned)(unsigned short)s) << 16;
    return z.f;
}

__device__ __forceinline__ void gld16(const short* g, short* l) {
    __builtin_amdgcn_global_load_lds(
        (const __attribute__((address_space(1))) void*)g,
        (__attribute__((address_space(3))) void*)l, 16, 0, 0);
}

// XCD-aware bijective block remap (T1).  n8 = (gx*gy)/8 per z-slice.
__device__ __forceinline__ void xcd_swz(int gx, int n8, int* bx, int* by) {
    const int lin = *bx + gx * (*by);        // XCD = lin&7
    const int nl  = (lin & 7) * n8 + (lin >> 3);
    *bx = nl % gx;
    *by = nl / gx;
}

// ---------------------------------------------------------------------------
// scan: per batch, compact unmasked key indices + both additive masks.
// ---------------------------------------------------------------------------
__global__ __launch_bounds__(256) void scan_kernel(
    const int* __restrict__ mask, int* __restrict__ idx, int* __restrict__ pos,
    int* __restrict__ cnt, float* __restrict__ maskc, float* __restrict__ maskf)
{
    const int b = blockIdx.x;
    const int t = threadIdx.x;
    const int lane = t & 63, wid = t >> 6;
    __shared__ int wsum[4];
    const int base = b * 2048 + t * 8;

    int fl[8]; int loc = 0;
    #pragma unroll
    for (int j = 0; j < 8; ++j) { fl[j] = (mask[base + j] == 0) ? 1 : 0; loc += fl[j]; }

    int inc = loc;
    #pragma unroll
    for (int d = 1; d < 64; d <<= 1) {
        const int n = __shfl_up(inc, d);
        if (lane >= d) inc += n;
    }
    if (lane == 63) wsum[wid] = inc;
    __syncthreads();
    int wbase = 0;
    for (int i = 0; i < wid; ++i) wbase += wsum[i];
    const int total = wsum[0] + wsum[1] + wsum[2] + wsum[3];

    int e = wbase + inc - loc;   // exclusive prefix for this thread
    #pragma unroll
    for (int j = 0; j < 8; ++j) {
        const int p = t * 8 + j;
        if (fl[j]) { idx[b * 2048 + e] = p; pos[base + j] = e; ++e; }
        else        pos[base + j] = -1;
        maskc[base + j] = (p < total) ? 0.f : NEGINF;
        maskf[base + j] = fl[j] ? 0.f : NEGINF;
        if (p >= total) idx[base + j] = 0;   // pad-safe gather source
    }
    if (t == 0) cnt[b] = total;
}

// ---------------------------------------------------------------------------
// cast_x: f32 -> bf16 straight copy of q/k/v.
// ---------------------------------------------------------------------------
__global__ __launch_bounds__(256) void cast_x_kernel(
    const float* __restrict__ q, const float* __restrict__ k, const float* __restrict__ v,
    short* __restrict__ Xq, short* __restrict__ Xk, short* __restrict__ Xv)
{
    const int which = blockIdx.y;
    const float* src = which == 0 ? q : (which == 1 ? k : v);
    short* dst       = which == 0 ? Xq : (which == 1 ? Xk : Xv);
    const int t = threadIdx.x;
    const size_t i = ((size_t)blockIdx.x * 256 + t) * 8;
    const float4 a = *reinterpret_cast<const float4*>(src + i);
    const float4 c = *reinterpret_cast<const float4*>(src + i + 4);
    bf16x8 o;
    o[0] = f2bf(a.x); o[1] = f2bf(a.y); o[2] = f2bf(a.z); o[3] = f2bf(a.w);
    o[4] = f2bf(c.x); o[5] = f2bf(c.y); o[6] = f2bf(c.z); o[7] = f2bf(c.w);
    *reinterpret_cast<bf16x8*>(dst + i) = o;
}

// ---------------------------------------------------------------------------
// cast_wt: W[k][n] f32 -> Wt[n][k] bf16 (transposed), 64x64 LDS tiles.
// ---------------------------------------------------------------------------
__global__ __launch_bounds__(256) void cast_wt_kernel(
    const float* __restrict__ Wq, const float* __restrict__ Wk,
    const float* __restrict__ Wv, const float* __restrict__ Wo,
    short* __restrict__ Wtq, short* __restrict__ Wtk,
    short* __restrict__ Wtv, short* __restrict__ Wto)
{
    const int which = blockIdx.z;
    const float* W = which == 0 ? Wq : (which == 1 ? Wk : (which == 2 ? Wv : Wo));
    short* Wt      = which == 0 ? Wtq : (which == 1 ? Wtk : (which == 2 ? Wtv : Wto));

    __shared__ float T[64][65];
    const int t = threadIdx.x;
    const int k0 = blockIdx.x * 64, n0 = blockIdx.y * 64;
    {
        const int row = t >> 2, cq = (t & 3) * 16;
        #pragma unroll
        for (int i = 0; i < 4; ++i) {
            const float4 v4 = *reinterpret_cast<const float4*>(&W[(size_t)(k0 + row) * 1024 + n0 + cq + i * 4]);
            T[row][cq + i * 4 + 0] = v4.x; T[row][cq + i * 4 + 1] = v4.y;
            T[row][cq + i * 4 + 2] = v4.z; T[row][cq + i * 4 + 3] = v4.w;
        }
    }
    __syncthreads();
    const int nl = t >> 2, kq = (t & 3) * 16;
    bf16x8 o0, o1;
    #pragma unroll
    for (int j = 0; j < 8; ++j) {
        o0[j] = f2bf(T[kq + j][nl]);
        o1[j] = f2bf(T[kq + 8 + j][nl]);
    }
    *reinterpret_cast<bf16x8*>(&Wt[(size_t)(n0 + nl) * 1024 + k0 + kq]) = o0;
    *reinterpret_cast<bf16x8*>(&Wt[(size_t)(n0 + nl) * 1024 + k0 + kq + 8]) = o1;
}

// ---------------------------------------------------------------------------
// proj: C = X(bf16)[M=8192,K=1024] @ Wt^T + bias.  128x128 tile, BK=32.
// XCD-swizzled.  which: 0->qh (scaled), 1->kh, 2->vT_c (compacted via pos).
// (round-13 proven bf16 path — 16KB LDS, 4 gld16/thread, zero conflicts)
// ---------------------------------------------------------------------------
__global__ __launch_bounds__(256) void proj_kernel(
    const short* __restrict__ Xq, const short* __restrict__ Xk, const short* __restrict__ Xv,
    const short* __restrict__ Wtq, const short* __restrict__ Wtk, const short* __restrict__ Wtv,
    const float* __restrict__ bq, const float* __restrict__ bk, const float* __restrict__ bv,
    const int* __restrict__ pos,
    short* __restrict__ qh, short* __restrict__ kh, short* __restrict__ vTc)
{
    const int which = blockIdx.z;
    const short* A  = which == 0 ? Xq : (which == 1 ? Xk : Xv);
    const short* Bt = which == 0 ? Wtq : (which == 1 ? Wtk : Wtv);
    const float* bias = which == 0 ? bq : (which == 1 ? bk : bv);

    __shared__ short Al[4096];   // [128 rows m][32 k], swizzled chunks
    __shared__ short Bl[4096];   // [128 rows n][32 k], swizzled chunks

    const int t = threadIdx.x;
    const int lane = t & 63, w = t >> 6;
    const int wm = w >> 1, wn = w & 1;
    const int g = lane >> 4, r16 = lane & 15;

    int bx = blockIdx.x, by = blockIdx.y;     // (8 n, 64 m)
    xcd_swz(8, 64, &bx, &by);
    const int m0 = by * 128, n0 = bx * 128;

    f32x4 acc[4][4] = {};

    for (int k0 = 0; k0 < 1024; k0 += 32) {
        __syncthreads();
        #pragma unroll
        for (int i = 0; i < 2; ++i) {
            const int row = i * 64 + (t >> 2);
            const int cl = (t & 3) ^ ((row >> 1) & 3);
            gld16(A  + (size_t)(m0 + row) * 1024 + k0 + cl * 8, Al + i * 2048 + t * 8);
            gld16(Bt + (size_t)(n0 + row) * 1024 + k0 + cl * 8, Bl + i * 2048 + t * 8);
        }
        __syncthreads();

        bf16x8 af[4], bf[4];
        #pragma unroll
        for (int mf = 0; mf < 4; ++mf) {
            const int row = wm * 64 + mf * 16 + r16;
            af[mf] = *reinterpret_cast<const bf16x8*>(
                (const char*)Al + row * 64 + (((g ^ ((row >> 1) & 3))) << 4));
        }
        #pragma unroll
        for (int nf = 0; nf < 4; ++nf) {
            const int row = wn * 64 + nf * 16 + r16;
            bf[nf] = *reinterpret_cast<const bf16x8*>(
                (const char*)Bl + row * 64 + (((g ^ ((row >> 1) & 3))) << 4));
        }
        #pragma unroll
        for (int mf = 0; mf < 4; ++mf)
            #pragma unroll
            for (int nf = 0; nf < 4; ++nf)
                acc[mf][nf] = MFMA(af[mf], bf[nf], acc[mf][nf]);
    }

    if (which < 2) {
        #pragma unroll
        for (int nf = 0; nf < 4; ++nf) {
            const int n = n0 + wn * 64 + nf * 16 + r16;
            const int h = n >> 6, dh = n & 63;
            const float bn = bias[n];
            #pragma unroll
            for (int mf = 0; mf < 4; ++mf) {
                #pragma unroll
                for (int r = 0; r < 4; ++r) {
                    const int m = m0 + wm * 64 + mf * 16 + 4 * g + r;
                    const int bb = m >> 11, l = m & 2047;
                    float vf = acc[mf][nf][r] + bn;
                    if (which == 0) vf *= QSCALE;       // base-2 logit domain
                    ((which == 0) ? qh : kh)[(((size_t)(bb * H_ + h)) * LQ_ + l) * 64 + dh] = f2bf(vf);
                }
            }
        }
    } else {
        int posr[4][4], bbr[4][4];
        #pragma unroll
        for (int mf = 0; mf < 4; ++mf)
            #pragma unroll
            for (int r = 0; r < 4; ++r) {
                const int m = m0 + wm * 64 + mf * 16 + 4 * g + r;
                const int bb = m >> 11, l = m & 2047;
                bbr[mf][r] = bb;
                posr[mf][r] = pos[bb * 2048 + l];
            }
        #pragma unroll
        for (int nf = 0; nf < 4; ++nf) {
            const int n = n0 + wn * 64 + nf * 16 + r16;
            const int h = n >> 6, dh = n & 63;
            const float bn = bias[n];
            #pragma unroll
            for (int mf = 0; mf < 4; ++mf) {
                #pragma unroll
                for (int r = 0; r < 4; ++r) {
                    const int pc = posr[mf][r];
                    if (pc >= 0)
                        vTc[(((size_t)(bbr[mf][r] * H_ + h)) * 64 + dh) * (size_t)LK_ + pc] =
                            f2bf(acc[mf][nf][r] + bn);
                }
            }
        }
    }
}

// ---------------------------------------------------------------------------
// flash: swapped-QK^T MFMA attention over COMPACTED keys.  8 waves / 128 q
// per block sharing the staged K/V tiles.  XCD-swizzled.  (round-13 proven)
// ---------------------------------------------------------------------------
__global__ __launch_bounds__(512) void flash_kernel(
    const short* __restrict__ qh, const short* __restrict__ kh, const short* __restrict__ vTc,
    const int* __restrict__ idx, const int* __restrict__ cnt, const float* __restrict__ maskc,
    short* __restrict__ ctx, float* __restrict__ mOut, float* __restrict__ sOut)
{
    int bx = blockIdx.x, by = blockIdx.y;     // (16 q, 16 h) = 256/slice
    xcd_swz(16, 32, &bx, &by);
    const int q0 = bx * 128;
    const int h  = by;
    const int b  = blockIdx.z;

    __shared__ short Kl[2][4096];   // [64 k_c][64 d] bf16, 16B-chunk swizzle (^row&7)
    __shared__ short Vl[2][4096];   // [64 dv][64 k_c] bf16, same swizzle

    const int t = threadIdx.x;
    const int lane = t & 63, w = t >> 6;     // 8 waves, wave owns q-rows w*16..w*16+15
    const int g = lane >> 4, q16 = lane & 15;

    const short* kbase = kh + (size_t)(b * H_ + h) * LK_ * 64;
    const short* vbase = vTc + (size_t)(b * H_ + h) * 64 * (size_t)LK_;
    const int*   idxb  = idx + b * 2048;
    const int nt = (cnt[b] + 63) >> 6;

    bf16x8 qf0, qf1;
    {
        const short* qrow = qh + ((size_t)(b * H_ + h) * LQ_ + q0 + w * 16 + q16) * 64;
        qf0 = *reinterpret_cast<const bf16x8*>(qrow + 8 * g);
        qf1 = *reinterpret_cast<const bf16x8*>(qrow + 32 + 8 * g);
    }

    f32x4 mlast[4] = {};
    if (nt > 0) {
        #pragma unroll
        for (int kb = 0; kb < 4; ++kb)
            mlast[kb] = *reinterpret_cast<const f32x4*>(
                maskc + b * 2048 + (nt - 1) * 64 + kb * 16 + 4 * g);
    }

    // staging map: 512 threads x 16B each = one full 64x64 bf16 tile
    const int srw = t >> 3, scl = t & 7;
    const int cl = scl ^ (srw & 7);

    f32x4 ot[4] = {};             // O^T frags: dv = 16*fc + 4g + r, q = q16
    float m_run = NEGINF, l_run = 0.f;

    if (nt > 0) {                 // prologue: stage compacted tile 0
        const int orig = idxb[srw];
        gld16(kbase + (size_t)orig * 64 + cl * 8, Kl[0] + t * 8);
        gld16(vbase + (size_t)srw * LK_ + cl * 8, Vl[0] + t * 8);
    }
    __syncthreads();

    int cur = 0;
    for (int kt = 0; kt < nt; ++kt) {
        if (kt + 1 < nt) {        // issue next tile's staging
            const int kn = (kt + 1) * 64;
            const int orig = idxb[kn + srw];
            gld16(kbase + (size_t)orig * 64 + cl * 8, Kl[cur ^ 1] + t * 8);
            gld16(vbase + (size_t)srw * LK_ + kn + cl * 8, Vl[cur ^ 1] + t * 8);
        }
        const bool lastt = (kt == nt - 1);

        // --- QK^T (swapped): S^T[k][q]; C-init = pad mask on last tile ---
        float lg[4][4];
        const short* klp = Kl[cur];
        __builtin_amdgcn_s_setprio(1);
        #pragma unroll
        for (int kb = 0; kb < 4; ++kb) {
            const int krow = kb * 16 + q16;
            const char* rowp = (const char*)klp + krow * 128;
            const int sw = (krow & 7) << 4;
            const bf16x8 kf0 = *reinterpret_cast<const bf16x8*>(rowp + ((g << 4) ^ sw));
            const bf16x8 kf1 = *reinterpret_cast<const bf16x8*>(rowp + (((4 + g) << 4) ^ sw));
            f32x4 s = lastt ? mlast[kb] : (f32x4){0.f, 0.f, 0.f, 0.f};
            s = MFMA(kf0, qf0, s);
            s = MFMA(kf1, qf1, s);
            #pragma unroll
            for (int r = 0; r < 4; ++r) lg[kb][r] = s[r];
        }
        __builtin_amdgcn_s_setprio(0);

        // --- online softmax (base-2), defer-rescale THR=8 ---
        float tm = NEGINF;
        #pragma unroll
        for (int kb = 0; kb < 4; ++kb)
            #pragma unroll
            for (int r = 0; r < 4; ++r) tm = fmaxf(tm, lg[kb][r]);
        tm = fmaxf(tm, __shfl_xor(tm, 16));
        tm = fmaxf(tm, __shfl_xor(tm, 32));

        const bool skip = __all(tm <= m_run + 8.0f);
        if (!skip) {
            const float m_new = fmaxf(m_run, tm);
            const float alpha = (m_run == NEGINF) ? 0.f : EXP2(m_run - m_new);
            #pragma unroll
            for (int fc = 0; fc < 4; ++fc)
                #pragma unroll
                for (int r = 0; r < 4; ++r) ot[fc][r] *= alpha;
            l_run *= alpha;
            m_run = m_new;
        }
        const float m_use = (m_run == NEGINF) ? 0.f : m_run;

        float p[4][4];
        float ls = 0.f;
        #pragma unroll
        for (int kb = 0; kb < 4; ++kb)
            #pragma unroll
            for (int r = 0; r < 4; ++r) { p[kb][r] = EXP2(lg[kb][r] - m_use); ls += p[kb][r]; }
        ls += __shfl_xor(ls, 16);
        ls += __shfl_xor(ls, 32);
        l_run += ls;

        // pack P^T to bf16 B-frags (k-bijection matches V^T A-frags)
        bf16x8 pb[2];
        #pragma unroll
        for (int r = 0; r < 4; ++r) {
            pb[0][r]     = f2bf(p[0][r]);
            pb[0][4 + r] = f2bf(p[1][r]);
            pb[1][r]     = f2bf(p[2][r]);
            pb[1][4 + r] = f2bf(p[3][r]);
        }

        // --- PV: O^T[dv][q] += mfma(V^T, P^T) ---
        const short* vlp = Vl[cur];
        __builtin_amdgcn_s_setprio(1);
        #pragma unroll
        for (int fc = 0; fc < 4; ++fc) {
            const int dvrow = fc * 16 + q16;
            const char* rowp = (const char*)vlp + dvrow * 128;
            const int sw = (dvrow & 7) << 4;
            #pragma unroll
            for (int tt = 0; tt < 2; ++tt) {
                const bf16x4 va = *reinterpret_cast<const bf16x4*>(rowp + ((64 * tt + 8 * g) ^ sw));
                const bf16x4 vb = *reinterpret_cast<const bf16x4*>(rowp + ((64 * tt + 32 + 8 * g) ^ sw));
                bf16x8 af;
                af[0] = va[0]; af[1] = va[1]; af[2] = va[2]; af[3] = va[3];
                af[4] = vb[0]; af[5] = vb[1]; af[6] = vb[2]; af[7] = vb[3];
                ot[fc] = MFMA(af, pb[tt], ot[fc]);
            }
        }
        __builtin_amdgcn_s_setprio(0);

        __syncthreads();   // drains next-tile gld16s; next iter reads cur^1
        cur ^= 1;
    }

    const float rs = (l_run > 0.f) ? 1.0f / l_run : 0.f;
    short* crow = ctx + ((size_t)b * LQ_ + q0 + w * 16 + q16) * (size_t)(H_ * 64) + h * 64;
    #pragma unroll
    for (int fc = 0; fc < 4; ++fc) {
        bf16x4 o4;
        #pragma unroll
        for (int r = 0; r < 4; ++r) o4[r] = f2bf(ot[fc][r] * rs);
        *reinterpret_cast<bf16x4*>(crow + fc * 16 + 4 * g) = o4;
    }
    if (lane < 16) {
        const size_t idxo = (size_t)(b * H_ + h) * LQ_ + q0 + w * 16 + lane;
        mOut[idxo] = m_run;
        sOut[idxo] = l_run;
    }
}

// ---------------------------------------------------------------------------
// avg: FULL-K, per-head K dbuf, 512 threads / 8 waves / 128 q-rows per block
// sharing the staged K-tile.  (round-8 proven kernel, verbatim — 92 us)
// ---------------------------------------------------------------------------
__global__ __launch_bounds__(512) void avg_kernel(
    const short* __restrict__ qh, const short* __restrict__ kh,
    const float* __restrict__ maskf,
    const float* __restrict__ mS, const float* __restrict__ sS,
    float* __restrict__ attn_avg)
{
    const int k0 = blockIdx.x * 64;
    const int q0 = blockIdx.y * 128;
    const int b  = blockIdx.z;

    __shared__ short Kl[2][4096];   // [buf][64 k x 64 d], 8KB each

    const int t = threadIdx.x;
    const int lane = t & 63, w = t >> 6;          // 8 waves
    const int g = lane >> 4, q16 = lane & 15;

    f32x4 mk[4];
    #pragma unroll
    for (int kb = 0; kb < 4; ++kb)
        mk[kb] = *reinterpret_cast<const f32x4*>(maskf + b * LK_ + k0 + kb * 16 + 4 * g);

    // staging map: 512 threads x 16B = full 64x64 bf16 tile, one gld16 each
    const int srw = t >> 3, scl = t & 7;          // row 0..63, chunk 0..7
    const int cl = scl ^ (srw & 7);
    const short* kbb = kh + ((size_t)b * H_ * LK_ + k0) * 64;   // + h*LK_*64

    const short* qbase = qh + ((size_t)b * H_ * LQ_ + q0 + w * 16 + q16) * 64;  // h-stride LQ_*64
    const size_t stbase = (size_t)b * H_ * LQ_ + q0 + w * 16 + q16;             // h-stride LQ_

    {   // prologue: stage head 0
        gld16(kbb + (size_t)srw * 64 + cl * 8, Kl[0] + t * 8);
    }
    bf16x8 qc0 = *reinterpret_cast<const bf16x8*>(qbase + 8 * g);
    bf16x8 qc1 = *reinterpret_cast<const bf16x8*>(qbase + 32 + 8 * g);
    float mc = mS[stbase], sc = sS[stbase];
    __syncthreads();

    f32x4 acc[4] = {};
    int cur = 0;
    for (int hh = 0; hh < H_; ++hh) {
        bf16x8 qn0, qn1; float mn = 0.f, sn = 0.f;
        if (hh + 1 < H_) {
            gld16(kbb + (size_t)(hh + 1) * LK_ * 64 + (size_t)srw * 64 + cl * 8,
                  Kl[cur ^ 1] + t * 8);
            const short* qp = qbase + (size_t)(hh + 1) * LQ_ * 64;
            qn0 = *reinterpret_cast<const bf16x8*>(qp + 8 * g);
            qn1 = *reinterpret_cast<const bf16x8*>(qp + 32 + 8 * g);
            mn = mS[stbase + (size_t)(hh + 1) * LQ_];
            sn = sS[stbase + (size_t)(hh + 1) * LQ_];
        }

        // fold 1/s into the exponent: exp2(l - m - log2 s)
        const float madj = (mc == NEGINF || sc <= 0.f)
                               ? __builtin_inff() : mc + __log2f(sc);

        const short* klp = Kl[cur];
        __builtin_amdgcn_s_setprio(1);
        #pragma unroll
        for (int kb = 0; kb < 4; ++kb) {
            const int krow = kb * 16 + q16;
            const char* rowp = (const char*)klp + krow * 128;
            const int sw = (krow & 7) << 4;
            const bf16x8 kf0 = *reinterpret_cast<const bf16x8*>(rowp + ((g << 4) ^ sw));
            const bf16x8 kf1 = *reinterpret_cast<const bf16x8*>(rowp + (((4 + g) << 4) ^ sw));
            f32x4 s = mk[kb];
            s = MFMA(kf0, qc0, s);
            s = MFMA(kf1, qc1, s);
            #pragma unroll
            for (int r = 0; r < 4; ++r)
                acc[kb][r] += EXP2(s[r] - madj);
        }
        __builtin_amdgcn_s_setprio(0);

        __syncthreads();   // drains next-head gld16; safe to flip buffers
        if (hh + 1 < H_) { qc0 = qn0; qc1 = qn1; mc = mn; sc = sn; }
        cur ^= 1;
    }

    const float scale = 1.0f / (float)H_;
    float* orow = attn_avg + ((size_t)b * LQ_ + q0 + w * 16 + q16) * (size_t)LK_ + k0;
    #pragma unroll
    for (int kb = 0; kb < 4; ++kb) {
        f32x4 o = acc[kb];
        o[0] *= scale; o[1] *= scale; o[2] *= scale; o[3] *= scale;
        *reinterpret_cast<f32x4*>(orow + kb * 16 + 4 * g) = o;
    }
}

// ---------------------------------------------------------------------------
// outproj: preln(bf16) = ctx(bf16) @ WoT^T + bo + resid.  XCD-swizzled.
// ---------------------------------------------------------------------------
__global__ __launch_bounds__(256) void outproj_kernel(
    const short* __restrict__ ctxIn, const short* __restrict__ Wto,
    const float* __restrict__ bo, const float* __restrict__ resid,
    short* __restrict__ preln)
{
    __shared__ short Al[4096];
    __shared__ short Bl[4096];

    const int t = threadIdx.x;
    const int lane = t & 63, w = t >> 6;
    const int wm = w >> 1, wn = w & 1;
    const int g = lane >> 4, r16 = lane & 15;

    int bx = blockIdx.x, by = blockIdx.y;     // (8 n, 64 m)
    xcd_swz(8, 64, &bx, &by);
    const int m0 = by * 128, n0 = bx * 128;

    f32x4 acc[4][4] = {};

    for (int k0 = 0; k0 < 1024; k0 += 32) {
        __syncthreads();
        #pragma unroll
        for (int i = 0; i < 2; ++i) {
            const int row = i * 64 + (t >> 2);
            const int cl = (t & 3) ^ ((row >> 1) & 3);
            gld16(ctxIn + (size_t)(m0 + row) * 1024 + k0 + cl * 8, Al + i * 2048 + t * 8);
            gld16(Wto   + (size_t)(n0 + row) * 1024 + k0 + cl * 8, Bl + i * 2048 + t * 8);
        }
        __syncthreads();

        bf16x8 af[4], bf[4];
        #pragma unroll
        for (int mf = 0; mf < 4; ++mf) {
            const int row = wm * 64 + mf * 16 + r16;
            af[mf] = *reinterpret_cast<const bf16x8*>(
                (const char*)Al + row * 64 + (((g ^ ((row >> 1) & 3))) << 4));
        }
        #pragma unroll
        for (int nf = 0; nf < 4; ++nf) {
            const int row = wn * 64 + nf * 16 + r16;
            bf[nf] = *reinterpret_cast<const bf16x8*>(
                (const char*)Bl + row * 64 + (((g ^ ((row >> 1) & 3))) << 4));
        }
        #pragma unroll
        for (int mf = 0; mf < 4; ++mf)
            #pragma unroll
            for (int nf = 0; nf < 4; ++nf)
                acc[mf][nf] = MFMA(af[mf], bf[nf], acc[mf][nf]);
    }

    #pragma unroll
    for (int nf = 0; nf < 4; ++nf) {
        const int n = n0 + wn * 64 + nf * 16 + r16;
        const float bn = bo[n];
        #pragma unroll
        for (int mf = 0; mf < 4; ++mf) {
            #pragma unroll
            for (int r = 0; r < 4; ++r) {
                const size_t m = m0 + wm * 64 + mf * 16 + 4 * g + r;
                preln[m * 1024 + n] = f2bf(acc[mf][nf][r] + bn + resid[m * 1024 + n]);
            }
        }
    }
}

// ---------------------------------------------------------------------------
// ln: LayerNorm over D=1024 from bf16 preln, one block per row, f32 out.
// ---------------------------------------------------------------------------
__global__ __launch_bounds__(256) void ln_kernel(
    const short* __restrict__ xin, const float* __restrict__ gam,
    const float* __restrict__ bet, float* __restrict__ out)
{
    const size_t row = blockIdx.x;
    const int t = threadIdx.x;
    const bf16x4 pv = *reinterpret_cast<const bf16x4*>(&xin[row * 1024 + t * 4]);
    float x[4];
    #pragma unroll
    for (int j = 0; j < 4; ++j) x[j] = bf2f(pv[j]);

    float s  = x[0] + x[1] + x[2] + x[3];
    float ss = x[0] * x[0] + x[1] * x[1] + x[2] * x[2] + x[3] * x[3];
    #pragma unroll
    for (int w = 1; w < 64; w <<= 1) { s += __shfl_xor(s, w); ss += __shfl_xor(ss, w); }

    __shared__ float rs_[4], rss_[4];
    if ((t & 63) == 0) { rs_[t >> 6] = s; rss_[t >> 6] = ss; }
    __syncthreads();
    s  = rs_[0] + rs_[1] + rs_[2] + rs_[3];
    ss = rss_[0] + rss_[1] + rss_[2] + rss_[3];

    const float mean = s * (1.0f / 1024.0f);
    const float var  = ss * (1.0f / 1024.0f) - mean * mean;
    const float rstd = rsqrtf(var + LN_EPS_);

    const float4 g4 = *reinterpret_cast<const float4*>(&gam[t * 4]);
    const float4 b4 = *reinterpret_cast<const float4*>(&bet[t * 4]);
    float4 o;
    o.x = (x[0] - mean) * rstd * g4.x + b4.x;
    o.y = (x[1] - mean) * rstd * g4.y + b4.y;
    o.z = (x[2] - mean) * rstd * g4.z + b4.z;
    o.w = (x[3] - mean) * rstd * g4.w + b4.w;
    *reinterpret_cast<float4*>(&out[row * 1024 + t * 4]) = o;
}

// ---------------------------------------------------------------------------
extern "C" void kernel_launch(void* const* d_in, const int* in_sizes, int n_in,
                              void* d_out, int out_size, void* d_ws, size_t ws_size,
                              hipStream_t stream)
{
    const float* q    = (const float*)d_in[0];
    const float* k    = (const float*)d_in[1];
    const float* v    = (const float*)d_in[2];
    const int*   mask = (const int*)d_in[3];
    const float* Wq   = (const float*)d_in[4];
    const float* bq   = (const float*)d_in[5];
    const float* Wk   = (const float*)d_in[6];
    const float* bk   = (const float*)d_in[7];
    const float* Wv   = (const float*)d_in[8];
    const float* bv   = (const float*)d_in[9];
    const float* Wo   = (const float*)d_in[10];
    const float* bo   = (const float*)d_in[11];
    const float* lng  = (const float*)d_in[12];
    const float* lnb  = (const float*)d_in[13];

    float* out      = (float*)d_out;                    // [B,LQ,D]
    float* attn_avg = out + (size_t)B_ * LQ_ * D_;      // [B,LQ,LK]

    const size_t XSZ = (size_t)B_ * LQ_ * D_;           // 8388608 elements
    const size_t WSZ = (size_t)D_ * D_;                 // 1048576

    short* Xq  = (short*)d_ws;
    short* Xk  = Xq + XSZ;
    short* Xv  = Xk + XSZ;
    short* Wtq = Xv + XSZ;
    short* Wtk = Wtq + WSZ;
    short* Wtv = Wtk + WSZ;
    short* Wto = Wtv + WSZ;
    short* qh  = Wto + WSZ;                             // [B,H,LQ,64] bf16 (pre-scaled)
    short* kh  = qh + XSZ;
    short* vTc = kh + XSZ;                              // [B,H,64,LK] bf16, COMPACTED cols
    float* mSt = (float*)(vTc + XSZ);                   // [B,H,LQ] base-2 max
    float* sSt = mSt + (size_t)B_ * H_ * LQ_;
    float* maskf = sSt + (size_t)B_ * H_ * LQ_;         // [B,LK] additive (full)
    float* maskc = maskf + (size_t)B_ * LK_;            // [B,LK] additive (compacted+pad)
    int*   idx   = (int*)(maskc + (size_t)B_ * LK_);    // [B,LK] compacted -> orig
    int*   pos   = idx + (size_t)B_ * LK_;              // [B,LK] orig -> compacted / -1
    int*   cnt   = pos + (size_t)B_ * LK_;              // [B]
    short* preln = qh;          // bf16, overlays qh (dead after avg)
    short* ctx   = Xv;          // overlays Xv (dead after proj)

    scan_kernel<<<dim3(B_), 256, 0, stream>>>(mask, idx, pos, cnt, maskc, maskf);
    cast_x_kernel<<<dim3(4096, 3), 256, 0, stream>>>(q, k, v, Xq, Xk, Xv);
    cast_wt_kernel<<<dim3(16, 16, 4), 256, 0, stream>>>(Wq, Wk, Wv, Wo, Wtq, Wtk, Wtv, Wto);

    proj_kernel<<<dim3(8, 64, 3), 256, 0, stream>>>(Xq, Xk, Xv, Wtq, Wtk, Wtv,
                                                    bq, bk, bv, pos, qh, kh, vTc);

    flash_kernel<<<dim3(16, 16, 4), 512, 0, stream>>>(qh, kh, vTc, idx, cnt, maskc,
                                                      ctx, mSt, sSt);

    avg_kernel<<<dim3(32, 16, 4), 512, 0, stream>>>(qh, kh, maskf, mSt, sSt, attn_avg);

    outproj_kernel<<<dim3(8, 64), 256, 0, stream>>>(ctx, Wto, bo, q, preln);

    ln_kernel<<<8192, 256, 0, stream>>>(preln, lng, lnb, out);
}